// Round 1
// baseline (727.716 us; speedup 1.0000x reference)
//
#include <hip/hip_runtime.h>

typedef __attribute__((ext_vector_type(8))) short short8;
typedef __attribute__((ext_vector_type(4))) short short4v;
typedef __attribute__((ext_vector_type(4))) float f32x4;

__device__ inline short f2bf(float f) {
    union { float f; unsigned u; } v; v.f = f;
    unsigned r = v.u + 0x7fffu + ((v.u >> 16) & 1u);
    return (short)(r >> 16);
}

// ---------------- elementwise f32 -> bf16 ----------------
__global__ __launch_bounds__(256) void cvt_f32_to_bf16(const float* __restrict__ in,
                                                       short* __restrict__ out, int n4) {
    int i = blockIdx.x * 256 + threadIdx.x;
    if (i >= n4) return;
    float4 v = ((const float4*)in)[i];
    short4v o;
    o[0] = f2bf(v.x); o[1] = f2bf(v.y); o[2] = f2bf(v.z); o[3] = f2bf(v.w);
    ((short4v*)out)[i] = o;
}

// ---------------- tiled transpose (R x C) -> bf16 (C x R), batched ----------------
__device__ inline short cvt_elem(float v) { return f2bf(v); }
__device__ inline short cvt_elem(short v) { return v; }

template <typename Tin>
__global__ __launch_bounds__(256) void transpose_to_bf16(const Tin* __restrict__ in,
                                                         short* __restrict__ out,
                                                         int R, int C) {
    __shared__ short tile[64][66];
    size_t base = (size_t)blockIdx.z * R * C;
    int r0 = blockIdx.x * 64, c0 = blockIdx.y * 64;
    int tid = threadIdx.x;
#pragma unroll
    for (int i = 0; i < 16; i++) {
        int idx = i * 256 + tid;
        int r = idx >> 6, c = idx & 63;
        tile[r][c] = cvt_elem(in[base + (size_t)(r0 + r) * C + (c0 + c)]);
    }
    __syncthreads();
#pragma unroll
    for (int i = 0; i < 16; i++) {
        int idx = i * 256 + tid;
        int c = idx >> 6, r = idx & 63;
        out[base + (size_t)(c0 + c) * R + (r0 + r)] = tile[r][c];
    }
}

// ---------------- bf16 GEMM: C(MxN) = A(MxK) * Bt(NxK)^T ----------------
// EPI 0: scatter into Q/K/V (B,H,S,dk) with Q scaled by qscale
// EPI 1: store f32 to OF (MxN)
template <int EPI>
__global__ __launch_bounds__(256) void gemm_bt(const short* __restrict__ A,
                                               const short* __restrict__ Bt,
                                               int M, int N, int K,
                                               short* __restrict__ O0, short* __restrict__ O1,
                                               short* __restrict__ O2, float* __restrict__ OF,
                                               float qscale) {
    __shared__ short Als[128 * 72];
    __shared__ short Bls[128 * 72];
    int tid = threadIdx.x;
    int lane = tid & 63, wid = tid >> 6;
    int wr = wid >> 1, wc = wid & 1;
    int ntn = N >> 7;
    int mt = blockIdx.x / ntn, nt = blockIdx.x % ntn;
    int row0 = mt << 7, col0 = nt << 7;
    int t15 = lane & 15, t4 = lane >> 4;

    f32x4 acc[4][4];
#pragma unroll
    for (int m = 0; m < 4; m++)
#pragma unroll
        for (int n = 0; n < 4; n++) acc[m][n] = (f32x4){0.f, 0.f, 0.f, 0.f};

    for (int k0 = 0; k0 < K; k0 += 64) {
        __syncthreads();
#pragma unroll
        for (int i = 0; i < 4; i++) {
            int ch = i * 256 + tid;
            int r = ch >> 3, c8 = (ch & 7) << 3;
            *(short8*)(Als + r * 72 + c8) = *(const short8*)(A + (size_t)(row0 + r) * K + k0 + c8);
            *(short8*)(Bls + r * 72 + c8) = *(const short8*)(Bt + (size_t)(col0 + r) * K + k0 + c8);
        }
        __syncthreads();
#pragma unroll
        for (int ks = 0; ks < 2; ks++) {
            short8 af[4], bfr[4];
#pragma unroll
            for (int m = 0; m < 4; m++)
                af[m] = *(short8*)(Als + (wr * 64 + m * 16 + t15) * 72 + ks * 32 + t4 * 8);
#pragma unroll
            for (int n = 0; n < 4; n++)
                bfr[n] = *(short8*)(Bls + (wc * 64 + n * 16 + t15) * 72 + ks * 32 + t4 * 8);
#pragma unroll
            for (int m = 0; m < 4; m++)
#pragma unroll
                for (int n = 0; n < 4; n++)
                    acc[m][n] = __builtin_amdgcn_mfma_f32_16x16x32_bf16(af[m], bfr[n], acc[m][n], 0, 0, 0);
        }
    }

#pragma unroll
    for (int m = 0; m < 4; m++) {
#pragma unroll
        for (int n = 0; n < 4; n++) {
#pragma unroll
            for (int r = 0; r < 4; r++) {
                float v = acc[m][n][r];
                int gm = row0 + wr * 64 + m * 16 + t4 * 4 + r;
                int gn = col0 + wc * 64 + n * 16 + t15;
                if (EPI == 0) {
                    int part = gn >> 11, within = gn & 2047;
                    int h = within >> 7, dk = within & 127;
                    int b = gm >> 11, s = gm & 2047;
                    size_t idx = ((size_t)(b * 16 + h) * 2048 + s) * 128 + dk;
                    if (part == 0) O0[idx] = f2bf(v * qscale);
                    else if (part == 1) O1[idx] = f2bf(v);
                    else O2[idx] = f2bf(v);
                } else {
                    OF[(size_t)gm * N + gn] = v;
                }
            }
        }
    }
}

// ---------------- causal flash attention ----------------
// Q,K: (64 heads)(2048 s)(128 dk) bf16, Q pre-scaled by 1/sqrt(128)
// Vt:  (64 heads)(128 dk)(2048 s) bf16
// O:   (4 b)(2048 s)(2048 d) bf16
__global__ __launch_bounds__(256) void attn_fwd(const short* __restrict__ Q,
                                                const short* __restrict__ Kb,
                                                const short* __restrict__ Vt,
                                                short* __restrict__ O) {
    __shared__ short Kls[64 * 136];
    __shared__ short Vls[128 * 72];
    __shared__ short Pls[4][16 * 72];
    int tid = threadIdx.x, lane = tid & 63, wid = tid >> 6;
    int qblk = blockIdx.x, z = blockIdx.y;
    int t15 = lane & 15, t4 = lane >> 4;
    const short* Qh = Q + (size_t)z * 2048 * 128;
    const short* Kh = Kb + (size_t)z * 2048 * 128;
    const short* Vh = Vt + (size_t)z * 128 * 2048;

    short8 qf[4];
    {
        const short* qrow = Qh + (size_t)(qblk * 64 + wid * 16 + t15) * 128;
#pragma unroll
        for (int s = 0; s < 4; s++) qf[s] = *(const short8*)(qrow + s * 32 + t4 * 8);
    }

    f32x4 o[8];
#pragma unroll
    for (int st = 0; st < 8; st++) o[st] = (f32x4){0.f, 0.f, 0.f, 0.f};
    float m_r[4], l_r[4];
#pragma unroll
    for (int r = 0; r < 4; r++) { m_r[r] = -1e30f; l_r[r] = 0.f; }

    for (int t = 0; t <= qblk; t++) {
        __syncthreads();
#pragma unroll
        for (int i = 0; i < 4; i++) {
            int ch = i * 256 + tid;
            {
                int r = ch >> 4, c8 = (ch & 15) << 3;
                *(short8*)(Kls + r * 136 + c8) =
                    *(const short8*)(Kh + (size_t)(t * 64 + r) * 128 + c8);
            }
            {
                int r = ch >> 3, c8 = (ch & 7) << 3;
                *(short8*)(Vls + r * 72 + c8) =
                    *(const short8*)(Vh + (size_t)r * 2048 + t * 64 + c8);
            }
        }
        __syncthreads();

        f32x4 sc[4];
#pragma unroll
        for (int c = 0; c < 4; c++) {
            sc[c] = (f32x4){0.f, 0.f, 0.f, 0.f};
#pragma unroll
            for (int s = 0; s < 4; s++) {
                short8 kf = *(short8*)(Kls + (c * 16 + t15) * 136 + s * 32 + t4 * 8);
                sc[c] = __builtin_amdgcn_mfma_f32_16x16x32_bf16(qf[s], kf, sc[c], 0, 0, 0);
            }
        }

        if (t == qblk) {
#pragma unroll
            for (int c = 0; c < 4; c++)
#pragma unroll
                for (int r = 0; r < 4; r++) {
                    int kv = c * 16 + t15, qq = wid * 16 + t4 * 4 + r;
                    if (kv > qq) sc[c][r] = -1e30f;
                }
        }

        float tm[4], rs[4];
#pragma unroll
        for (int r = 0; r < 4; r++) {
            tm[r] = fmaxf(fmaxf(sc[0][r], sc[1][r]), fmaxf(sc[2][r], sc[3][r]));
#pragma unroll
            for (int msk = 1; msk <= 8; msk <<= 1)
                tm[r] = fmaxf(tm[r], __shfl_xor(tm[r], msk));
        }
#pragma unroll
        for (int r = 0; r < 4; r++) {
            float mn = fmaxf(m_r[r], tm[r]);
            float scf = __expf(m_r[r] - mn);
            m_r[r] = mn;
            l_r[r] *= scf;
#pragma unroll
            for (int st = 0; st < 8; st++) o[st][r] *= scf;
            rs[r] = 0.f;
#pragma unroll
            for (int c = 0; c < 4; c++) {
                float p = __expf(sc[c][r] - mn);
                sc[c][r] = p;
                rs[r] += p;
            }
#pragma unroll
            for (int msk = 1; msk <= 8; msk <<= 1) rs[r] += __shfl_xor(rs[r], msk);
            l_r[r] += rs[r];
        }

#pragma unroll
        for (int c = 0; c < 4; c++)
#pragma unroll
            for (int r = 0; r < 4; r++)
                Pls[wid][(t4 * 4 + r) * 72 + c * 16 + t15] = f2bf(sc[c][r]);

        __syncthreads();  // safety barrier (wave-local P staging; remove after verification)

        short8 pa[2];
#pragma unroll
        for (int s2 = 0; s2 < 2; s2++)
            pa[s2] = *(short8*)(&Pls[wid][0] + t15 * 72 + s2 * 32 + t4 * 8);
#pragma unroll
        for (int st = 0; st < 8; st++) {
#pragma unroll
            for (int s2 = 0; s2 < 2; s2++) {
                short8 vf = *(short8*)(Vls + (st * 16 + t15) * 72 + s2 * 32 + t4 * 8);
                o[st] = __builtin_amdgcn_mfma_f32_16x16x32_bf16(pa[s2], vf, o[st], 0, 0, 0);
            }
        }
    }

    int b = z >> 4, h = z & 15;
#pragma unroll
    for (int st = 0; st < 8; st++)
#pragma unroll
        for (int r = 0; r < 4; r++) {
            int s = qblk * 64 + wid * 16 + t4 * 4 + r;
            float val = o[st][r] / l_r[r];
            O[((size_t)b * 2048 + s) * 2048 + h * 128 + st * 16 + t15] = f2bf(val);
        }
}

extern "C" void kernel_launch(void* const* d_in, const int* in_sizes, int n_in,
                              void* d_out, int out_size, void* d_ws, size_t ws_size,
                              hipStream_t stream) {
    const float* x = (const float*)d_in[0];      // (4,2048,2048)
    const float* Wqkv = (const float*)d_in[1];   // (2048,6144)
    const float* Wo = (const float*)d_in[2];     // (2048,2048)

    const int B = 4, S = 2048, D = 2048, H = 16, DK = 128;
    const int M = B * S;          // 8192
    const int N1 = 3 * D;         // 6144
    (void)in_sizes; (void)n_in; (void)out_size; (void)ws_size;

    char* ws = (char*)d_ws;
    size_t off = 0;
    short* x_bf = (short*)(ws + off);   off += (size_t)M * D * 2;        // 32 MiB
    short* wqkv_t = (short*)(ws + off); off += (size_t)N1 * D * 2;       // 24 MiB
    short* wo_t = (short*)(ws + off);   off += (size_t)D * D * 2;        // 8 MiB
    short* Qb = (short*)(ws + off);     off += (size_t)B * H * S * DK * 2;
    short* Kb = (short*)(ws + off);     off += (size_t)B * H * S * DK * 2;
    short* Vb = (short*)(ws + off);     off += (size_t)B * H * S * DK * 2;
    short* Vt = (short*)(ws + off);     off += (size_t)B * H * S * DK * 2;
    short* Ob = (short*)(ws + off);     off += (size_t)M * D * 2;

    // 1. x -> bf16
    cvt_f32_to_bf16<<<(M * D / 4 + 255) / 256, 256, 0, stream>>>(x, x_bf, M * D / 4);
    // 2. Wqkv^T -> bf16 (N1 x D)
    transpose_to_bf16<float><<<dim3(D / 64, N1 / 64, 1), 256, 0, stream>>>(Wqkv, wqkv_t, D, N1);
    // 3. Wo^T -> bf16 (D x D)
    transpose_to_bf16<float><<<dim3(D / 64, D / 64, 1), 256, 0, stream>>>(Wo, wo_t, D, D);
    // 4. GEMM1: qkv = x @ Wqkv, scattered to Q(scaled)/K/V
    gemm_bt<0><<<(M / 128) * (N1 / 128), 256, 0, stream>>>(
        x_bf, wqkv_t, M, N1, D, Qb, Kb, Vb, nullptr, 0.08838834764831845f);
    // 5. V -> Vt (per-head transpose: (S,dk) -> (dk,S))
    transpose_to_bf16<short><<<dim3(S / 64, DK / 64, B * H), 256, 0, stream>>>(Vb, Vt, S, DK);
    // 6. attention
    attn_fwd<<<dim3(S / 64, B * H), 256, 0, stream>>>(Qb, Kb, Vt, Ob);
    // 7. GEMM2: out = O @ Wo (f32 store)
    gemm_bt<1><<<(M / 128) * (D / 128), 256, 0, stream>>>(
        Ob, wo_t, M, D, D, nullptr, nullptr, nullptr, (float*)d_out, 1.0f);
}